// Round 10
// baseline (2654.346 us; speedup 1.0000x reference)
//
#include <hip/hip_runtime.h>
#include <math.h>

// ---------------------------------------------------------------------------
// MPNN forward (N=10000 nodes, E=40000 edges, B=250 graphs, H=64, RD=1024)
//
// agg[d,o] = sum_{k,i} G[d,k,i] * W2n[k*64+i, o]
//   where G[d,k,:] = sum_{e in in(d)} ef[e,k] * h[src_e,:]   (N x 896)
// Dense phase: aggg (split-K z=7 -> 7 partials) -> sumrelu -> gigh -> gru.
// CSR by dst built once; sparse phase gathers h (L2-resident) only.
// ---------------------------------------------------------------------------

#define H 64
#define NODE_IN 74
#define EDGE_IN 12
#define EF 14            // EDGE_IN + gate + 1.0 (bias slot)
#define GCAP 256         // per-graph node-list capacity
#define NZ 7             // split-K factor for aggg (896 = 7*128)

__device__ __forceinline__ float sigmoidf(float x) {
    return 1.0f / (1.0f + expf(-x));
}

// ---------------------------------------------------------------------------
// 64x64-tile f32 GEMM with PReLU epilogue (final projection only).
// ---------------------------------------------------------------------------
__global__ __launch_bounds__(256)
void gemm_prelu_k(const float* __restrict__ A, int lda,
                  const float* __restrict__ B, int ldb,
                  float* __restrict__ C, int ldc,
                  int M, int N, int K,
                  const float* __restrict__ cbias,
                  const float* __restrict__ prelu_a)
{
    __shared__ float sA[64][68];
    __shared__ float sB[64][68];
    const int tid = threadIdx.x;
    const int bm  = blockIdx.x * 64;
    const int bn  = blockIdx.y * 64;
    const int tx  = tid & 15;
    const int ty  = tid >> 4;
    float acc[4][4] = {{0.f}};

    for (int k0 = 0; k0 < K; k0 += 64) {
        #pragma unroll
        for (int t = 0; t < 4; ++t) {
            int idx = tid + t * 256;
            int r   = idx >> 4;
            int c   = (idx & 15) << 2;
            float4 v = {0.f, 0.f, 0.f, 0.f};
            int gm = bm + r;
            if (gm < M)
                v = *reinterpret_cast<const float4*>(A + (size_t)gm * lda + (k0 + c));
            sA[c + 0][r] = v.x; sA[c + 1][r] = v.y;
            sA[c + 2][r] = v.z; sA[c + 3][r] = v.w;
        }
        #pragma unroll
        for (int t = 0; t < 4; ++t) {
            int idx = tid + t * 256;
            int r   = idx >> 4;
            int c   = (idx & 15) << 2;
            *reinterpret_cast<float4*>(&sB[r][c]) =
                *reinterpret_cast<const float4*>(B + (size_t)(k0 + r) * ldb + (bn + c));
        }
        __syncthreads();
        #pragma unroll
        for (int kk = 0; kk < 64; ++kk) {
            float4 av = *reinterpret_cast<const float4*>(&sA[kk][ty * 4]);
            float4 bv = *reinterpret_cast<const float4*>(&sB[kk][tx * 4]);
            float ar[4] = {av.x, av.y, av.z, av.w};
            float br[4] = {bv.x, bv.y, bv.z, bv.w};
            #pragma unroll
            for (int i = 0; i < 4; ++i)
                #pragma unroll
                for (int j = 0; j < 4; ++j)
                    acc[i][j] = fmaf(ar[i], br[j], acc[i][j]);
        }
        __syncthreads();
    }

    float pa = prelu_a[0];
    #pragma unroll
    for (int i = 0; i < 4; ++i) {
        int gm = bm + ty * 4 + i;
        if (gm < M) {
            float4 v;
            float* vv = reinterpret_cast<float*>(&v);
            #pragma unroll
            for (int j = 0; j < 4; ++j) {
                float c = acc[i][j] + cbias[bn + tx * 4 + j];
                vv[j] = (c >= 0.f) ? c : pa * c;
            }
            *reinterpret_cast<float4*>(C + (size_t)gm * ldc + bn + tx * 4) = v;
        }
    }
}

// ---------------------------------------------------------------------------
// aggP[z] = G[:, z*128:(z+1)*128] @ W2n[z*128:(z+1)*128, :]   (N x 64 each)
// grid (157, 7): blockIdx.y = z. 64x64 tile, 4x4 acc.
// sA pad 65 + scalar stores/reads: bank-conflict-free (2-way max on stores,
// 16-lane broadcast on reads). sB pad 68 (aligned b128).
// ---------------------------------------------------------------------------
__global__ __launch_bounds__(256)
void aggg_k(const float* __restrict__ G, const float* __restrict__ W2n,
            float* __restrict__ aggP, int M)
{
    __shared__ float sA[64][65];
    __shared__ float sB[64][68];
    const int tid = threadIdx.x;
    const int bm  = blockIdx.x * 64;
    const int z   = blockIdx.y;
    const int tx  = tid & 15;
    const int ty  = tid >> 4;
    float* C = aggP + (size_t)z * M * 64;
    float acc[4][4] = {{0.f}};
    const int kbase = z * 128;

    #pragma unroll
    for (int k0 = kbase; k0 < kbase + 128; k0 += 64) {
        #pragma unroll
        for (int t = 0; t < 4; ++t) {
            int idx = tid + t * 256;
            int r   = idx >> 4;
            int c   = (idx & 15) << 2;
            float4 v = {0.f, 0.f, 0.f, 0.f};
            int gm = bm + r;
            if (gm < M)
                v = *reinterpret_cast<const float4*>(G + (size_t)gm * 896 + (k0 + c));
            sA[c + 0][r] = v.x; sA[c + 1][r] = v.y;
            sA[c + 2][r] = v.z; sA[c + 3][r] = v.w;
        }
        #pragma unroll
        for (int t = 0; t < 4; ++t) {
            int idx = tid + t * 256;
            int r   = idx >> 4;
            int c   = (idx & 15) << 2;
            *reinterpret_cast<float4*>(&sB[r][c]) =
                *reinterpret_cast<const float4*>(W2n + (size_t)(k0 + r) * 64 + c);
        }
        __syncthreads();
        #pragma unroll
        for (int kk = 0; kk < 64; ++kk) {
            float a0 = sA[kk][ty * 4 + 0];
            float a1 = sA[kk][ty * 4 + 1];
            float a2 = sA[kk][ty * 4 + 2];
            float a3 = sA[kk][ty * 4 + 3];
            float4 bv = *reinterpret_cast<const float4*>(&sB[kk][tx * 4]);
            float ar[4] = {a0, a1, a2, a3};
            float br[4] = {bv.x, bv.y, bv.z, bv.w};
            #pragma unroll
            for (int i = 0; i < 4; ++i)
                #pragma unroll
                for (int j = 0; j < 4; ++j)
                    acc[i][j] = fmaf(ar[i], br[j], acc[i][j]);
        }
        __syncthreads();
    }
    #pragma unroll
    for (int i = 0; i < 4; ++i) {
        int gm = bm + ty * 4 + i;
        if (gm < M)
            *reinterpret_cast<float4*>(C + (size_t)gm * 64 + tx * 4) =
                make_float4(acc[i][0], acc[i][1], acc[i][2], acc[i][3]);
    }
}

// ---------------------------------------------------------------------------
// aggR = relu(sum_z aggP[z] + nb)   (N x 64), float4-vectorized
// ---------------------------------------------------------------------------
__global__ __launch_bounds__(256)
void sumrelu_k(const float* __restrict__ aggP, const float* __restrict__ nb,
               float* __restrict__ aggR, int M)
{
    int idx = blockIdx.x * 256 + threadIdx.x;      // float4 index
    if (idx >= M * 16) return;
    int o4 = idx & 15;
    float4 s = *reinterpret_cast<const float4*>(nb + o4 * 4);
    size_t stride = (size_t)M * 16;
    const float4* p = reinterpret_cast<const float4*>(aggP) + idx;
    #pragma unroll
    for (int z = 0; z < NZ; ++z) {
        float4 v = p[z * stride];
        s.x += v.x; s.y += v.y; s.z += v.z; s.w += v.w;
    }
    s.x = fmaxf(s.x, 0.f); s.y = fmaxf(s.y, 0.f);
    s.z = fmaxf(s.z, 0.f); s.w = fmaxf(s.w, 0.f);
    reinterpret_cast<float4*>(aggR)[idx] = s;
}

// ---------------------------------------------------------------------------
// gi / gh: grid (157, 6). y<3: gi = aggR @ wihT (col slice y);
//          y>=3: gh = h @ whhT (col slice y-3). K=64 single iteration.
// Uniform per-block selects (SGPR); sA pad-65 scalar path (conflict-free).
// ---------------------------------------------------------------------------
__global__ __launch_bounds__(256)
void gigh_k(const float* __restrict__ aggR, const float* __restrict__ h,
            const float* __restrict__ wihT, const float* __restrict__ whhT,
            float* __restrict__ gib, float* __restrict__ ghb, int M)
{
    __shared__ float sA[64][65];
    __shared__ float sB[64][68];
    const int tid = threadIdx.x;
    const int bm  = blockIdx.x * 64;
    const int yy  = blockIdx.y;
    const int sec = (yy >= 3) ? 1 : 0;
    const int bn  = (sec ? yy - 3 : yy) * 64;
    const float* A  = sec ? h : aggR;
    const float* Bm = sec ? whhT : wihT;
    float*       C  = sec ? ghb : gib;
    const int tx = tid & 15;
    const int ty = tid >> 4;
    float acc[4][4] = {{0.f}};

    #pragma unroll
    for (int t = 0; t < 4; ++t) {
        int idx = tid + t * 256;
        int r   = idx >> 4;
        int c   = (idx & 15) << 2;
        float4 v = {0.f, 0.f, 0.f, 0.f};
        int gm = bm + r;
        if (gm < M)
            v = *reinterpret_cast<const float4*>(A + (size_t)gm * 64 + c);
        sA[c + 0][r] = v.x; sA[c + 1][r] = v.y;
        sA[c + 2][r] = v.z; sA[c + 3][r] = v.w;
    }
    #pragma unroll
    for (int t = 0; t < 4; ++t) {
        int idx = tid + t * 256;
        int r   = idx >> 4;
        int c   = (idx & 15) << 2;
        *reinterpret_cast<float4*>(&sB[r][c]) =
            *reinterpret_cast<const float4*>(Bm + (size_t)r * 192 + (bn + c));
    }
    __syncthreads();
    #pragma unroll
    for (int kk = 0; kk < 64; ++kk) {
        float a0 = sA[kk][ty * 4 + 0];
        float a1 = sA[kk][ty * 4 + 1];
        float a2 = sA[kk][ty * 4 + 2];
        float a3 = sA[kk][ty * 4 + 3];
        float4 bv = *reinterpret_cast<const float4*>(&sB[kk][tx * 4]);
        float ar[4] = {a0, a1, a2, a3};
        float br[4] = {bv.x, bv.y, bv.z, bv.w};
        #pragma unroll
        for (int i = 0; i < 4; ++i)
            #pragma unroll
            for (int j = 0; j < 4; ++j)
                acc[i][j] = fmaf(ar[i], br[j], acc[i][j]);
    }
    #pragma unroll
    for (int i = 0; i < 4; ++i) {
        int gm = bm + ty * 4 + i;
        if (gm < M)
            *reinterpret_cast<float4*>(C + (size_t)gm * 192 + bn + tx * 4) =
                make_float4(acc[i][0], acc[i][1], acc[i][2], acc[i][3]);
    }
}

// ---------------------------------------------------------------------------
// Fused prologue (block-range split): h0 | weight re-layouts | degrees | glist
// ---------------------------------------------------------------------------
__global__ __launch_bounds__(256)
void prep_all_k(const float* __restrict__ na, const float* __restrict__ Wp,
                const float* __restrict__ bp, float* __restrict__ h0,
                const float* __restrict__ We, const float* __restrict__ be,
                const float* __restrict__ wih, const float* __restrict__ whh,
                const float* __restrict__ lwih, const float* __restrict__ lwhh,
                const float* __restrict__ Ws,
                float* __restrict__ W2n, float* __restrict__ wihT,
                float* __restrict__ whhT, float* __restrict__ WlT,
                float* __restrict__ WsT,
                const int* __restrict__ dst, float* __restrict__ deg,
                int* __restrict__ icnt,
                const int* __restrict__ gid, int* __restrict__ gcnt,
                int* __restrict__ glist,
                int N, int E,
                int nb_h0, int nb_prep, int nb_deg)
{
    int b   = blockIdx.x;
    int tid = threadIdx.x;
    if (b < nb_h0) {
        int idx = b * 256 + tid;
        if (idx >= N * H) return;
        int n = idx >> 6, o = idx & 63;
        const float* x = na + (size_t)n * NODE_IN;
        const float* w = Wp + (size_t)o * NODE_IN;
        float acc = bp[o];
        #pragma unroll
        for (int k = 0; k < NODE_IN; ++k) acc = fmaf(x[k], w[k], acc);
        h0[idx] = fmaxf(acc, 0.f);
    } else if (b < nb_h0 + nb_prep) {
        int t = (b - nb_h0) * 256 + tid;
        if (t < 57344) {
            // W2n[(k*64+i)*64 + o] = k<13 ? We[(i*64+o)*13+k] : be[i*64+o]
            int ko = t >> 6, o = t & 63;
            int k = ko >> 6, i = ko & 63;
            W2n[t] = (k < 13) ? We[(size_t)(i * 64 + o) * 13 + k] : be[i * 64 + o];
        } else if (t < 69632) {
            int u = t - 57344;
            int i = u / 192, j = u % 192;
            wihT[u] = wih[(size_t)j * 64 + i];
        } else if (t < 81920) {
            int u = t - 69632;
            int i = u / 192, j = u % 192;
            whhT[u] = whh[(size_t)j * 64 + i];
        } else if (t < 278528) {
            int u = t - 81920;              // k*512 + j
            int k = u >> 9, j = u & 511;
            WlT[u] = (k < 256) ? lwih[(size_t)j * 256 + k]
                               : lwhh[(size_t)j * 128 + (k - 256)];
        } else if (t < 540672) {
            int u = t - 278528;             // k*1024 + j
            int k = u >> 10, j = u & 1023;
            WsT[u] = Ws[(size_t)j * 256 + k];
        }
    } else if (b < nb_h0 + nb_prep + nb_deg) {
        int e = (b - nb_h0 - nb_prep) * 256 + tid;
        if (e < E) {
            int d = dst[e];
            atomicAdd(&deg[d], 1.0f);
            atomicAdd(&icnt[d], 1);
        }
    } else {
        int n = (b - nb_h0 - nb_prep - nb_deg) * 256 + tid;
        if (n < N) {
            int g = gid[n];
            int p = atomicAdd(&gcnt[g], 1);
            if (p < GCAP) glist[(size_t)g * GCAP + p] = n;
        }
    }
}

// ---------------------------------------------------------------------------
// Exclusive scan of icnt[N] -> row_ptr[N+1], cursor[N]. Single block,
// shuffle-based wave scans.
// ---------------------------------------------------------------------------
__global__ __launch_bounds__(1024)
void scan_k(const int* __restrict__ icnt, int* __restrict__ row_ptr,
            int* __restrict__ cursor, int N)
{
    __shared__ int wsum[16];
    __shared__ int carrySh;
    int tid  = threadIdx.x;
    int lane = tid & 63;
    int wid  = tid >> 6;
    if (tid == 0) { carrySh = 0; row_ptr[0] = 0; }
    __syncthreads();
    for (int base = 0; base < N; base += 1024) {
        int i = base + tid;
        int v = (i < N) ? icnt[i] : 0;
        int x = v;
        #pragma unroll
        for (int off = 1; off < 64; off <<= 1) {
            int t = __shfl_up(x, off);
            if (lane >= off) x += t;
        }
        if (lane == 63) wsum[wid] = x;
        __syncthreads();
        if (wid == 0) {
            int s = (lane < 16) ? wsum[lane] : 0;
            #pragma unroll
            for (int off = 1; off < 16; off <<= 1) {
                int t = __shfl_up(s, off);
                if (lane >= off) s += t;
            }
            if (lane < 16) wsum[lane] = s;
        }
        __syncthreads();
        int woff = (wid > 0) ? wsum[wid - 1] : 0;
        int incl = x + woff + carrySh;
        if (i < N) { row_ptr[i + 1] = incl; cursor[i] = incl - v; }
        __syncthreads();
        if (tid == 1023) carrySh = incl;
        __syncthreads();
    }
}

// ---------------------------------------------------------------------------
// FALayer gate -> ef[e] = [edge_attr(12), gate, 1.0]; lane 14 fills CSR slot.
// ---------------------------------------------------------------------------
__global__ __launch_bounds__(256)
void gate_k(const float* __restrict__ h0, const float* __restrict__ ea,
            const int* __restrict__ src, const int* __restrict__ dst,
            const float* __restrict__ Wg, const float* __restrict__ bg,
            const float* __restrict__ deg, float* __restrict__ ef,
            int* __restrict__ cursor, int* __restrict__ csr_eid, int E)
{
    int e    = blockIdx.x * 4 + (threadIdx.x >> 6);
    int lane = threadIdx.x & 63;
    if (e >= E) return;
    int s = src[e], d = dst[e];
    float v = Wg[lane]      * h0[(size_t)d * H + lane]
            + Wg[H + lane]  * h0[(size_t)s * H + lane];
    #pragma unroll
    for (int off = 32; off; off >>= 1) v += __shfl_xor(v, off);
    if (lane < EF) {
        float out;
        if (lane < EDGE_IN) out = ea[(size_t)e * EDGE_IN + lane];
        else if (lane == EDGE_IN) {
            float t = tanhf(v + bg[0]);
            out = 0.3f + t * deg[d] * deg[s];
        } else out = 1.0f;
        ef[(size_t)e * EF + lane] = out;
    } else if (lane == EF) {
        int pos = atomicAdd(&cursor[d], 1);
        csr_eid[pos] = e;
    }
}

// ---------------------------------------------------------------------------
// Sparse phase: G[d,k,:] = sum_{e in in(d)} ef[e,k] * h[src_e,:]
// One wave per dst node (lane = h channel); h is L2-resident (2.5 MB).
// ---------------------------------------------------------------------------
__global__ __launch_bounds__(256)
void sparseG_k(const float* __restrict__ h, const float* __restrict__ ef,
               const int* __restrict__ src, const int* __restrict__ csr_eid,
               const int* __restrict__ rowp, float* __restrict__ G, int N)
{
    int n    = blockIdx.x * 4 + (threadIdx.x >> 6);
    int lane = threadIdx.x & 63;
    if (n >= N) return;
    float g[EF];
    #pragma unroll
    for (int k = 0; k < EF; ++k) g[k] = 0.f;
    int p0 = rowp[n], p1 = rowp[n + 1];
    for (int p = p0; p < p1; ++p) {
        int e = csr_eid[p];
        float hv = h[(size_t)src[e] * H + lane];
        const float* f = ef + (size_t)e * EF;
        #pragma unroll
        for (int k = 0; k < EF; ++k) g[k] = fmaf(f[k], hv, g[k]);
    }
    float* Gr = G + (size_t)n * (EF * H);
    #pragma unroll
    for (int k = 0; k < EF; ++k) Gr[k * H + lane] = g[k];
}

// ---------------------------------------------------------------------------
// GRU elementwise (torch gate order r,z,n); biases folded here.
// ---------------------------------------------------------------------------
__global__ __launch_bounds__(256)
void gru_k(const float* __restrict__ gi, const float* __restrict__ gh,
           const float* __restrict__ bih, const float* __restrict__ bhh,
           const float* __restrict__ hin, float* __restrict__ hout, int N)
{
    int idx = blockIdx.x * 256 + threadIdx.x;
    if (idx >= N * H) return;
    int n = idx >> 6, o = idx & 63;
    const float* gin = gi + (size_t)n * 192;
    const float* ghn = gh + (size_t)n * 192;
    float r  = sigmoidf(gin[o]       + bih[o]       + ghn[o]       + bhh[o]);
    float z  = sigmoidf(gin[64 + o]  + bih[64 + o]  + ghn[64 + o]  + bhh[64 + o]);
    float gn = ghn[128 + o] + bhh[128 + o];
    float ng = tanhf(gin[128 + o] + bih[128 + o] + r * gn);
    float hv = hin[idx];
    hout[idx] = (1.f - z) * ng + z * hv;
}

// ---------------------------------------------------------------------------
// Fully fused Set2Set step, one 256-thread block per graph.
// Acat[b] = [q_star (q|readout) (256) | hl (128)].
// ---------------------------------------------------------------------------
__global__ __launch_bounds__(256)
void att256_k(const float* __restrict__ h0, const float* __restrict__ h,
              const float* __restrict__ WlT,
              const float* __restrict__ lbih, const float* __restrict__ lbhh,
              float* __restrict__ cl,
              const int* __restrict__ glist, const int* __restrict__ gcnt,
              float* __restrict__ Acat)
{
    int b    = blockIdx.x;
    int tid  = threadIdx.x;
    int lane = tid & 63;
    int wid  = tid >> 6;
    __shared__ float acatS[384];
    __shared__ float g4s[512];
    __shared__ float q[128];
    __shared__ float sc[GCAP];
    __shared__ float red[8];

    for (int j = tid; j < 384; j += 256) acatS[j] = Acat[(size_t)b * 384 + j];
    __syncthreads();

    for (int j = tid; j < 512; j += 256) {
        float s = 0.f;
        for (int k = 0; k < 384; ++k)
            s = fmaf(acatS[k], WlT[(size_t)k * 512 + j], s);
        g4s[j] = s;
    }
    __syncthreads();

    if (tid < 128) {
        int d = tid;
        float ii = sigmoidf(g4s[d]       + lbih[d]       + lbhh[d]);
        float ff = sigmoidf(g4s[128 + d] + lbih[128 + d] + lbhh[128 + d]);
        float gg = tanhf  (g4s[256 + d] + lbih[256 + d] + lbhh[256 + d]);
        float oo = sigmoidf(g4s[384 + d] + lbih[384 + d] + lbhh[384 + d]);
        float c  = ff * cl[(size_t)b * 128 + d] + ii * gg;
        cl[(size_t)b * 128 + d] = c;
        q[d] = oo * tanhf(c);
    }
    __syncthreads();

    int c = gcnt[b]; if (c > GCAP) c = GCAP;

    float lmax = -INFINITY;
    for (int i = wid; i < c; i += 4) {
        int n = glist[(size_t)b * GCAP + i];
        float v = h0[(size_t)n * H + lane] * q[lane]
                + h [(size_t)n * H + lane] * q[64 + lane];
        #pragma unroll
        for (int off = 32; off; off >>= 1) v += __shfl_xor(v, off);
        if (lane == 0) sc[i] = v;
        lmax = fmaxf(lmax, v);
    }
    if (lane == 0) red[wid] = lmax;
    __syncthreads();
    lmax = fmaxf(fmaxf(red[0], red[1]), fmaxf(red[2], red[3]));

    float lsum = 0.f;
    for (int i = tid; i < c; i += 256) {
        float e = expf(sc[i] - lmax);
        sc[i] = e;
        lsum += e;
    }
    #pragma unroll
    for (int off = 32; off; off >>= 1) lsum += __shfl_xor(lsum, off);
    if (lane == 0) red[4 + wid] = lsum;
    __syncthreads();
    float inv = 1.f / (red[4] + red[5] + red[6] + red[7]);

    float r = 0.f;
    if (tid < 128) {
        const float* srcf = (tid < 64) ? h0 : h;
        for (int i = 0; i < c; ++i) {
            int n = glist[(size_t)b * GCAP + i];
            r = fmaf(sc[i], srcf[(size_t)n * H + lane], r);
        }
    }
    float* A = Acat + (size_t)b * 384;
    if (tid < 128) {
        A[tid]       = q[tid];
        A[128 + tid] = r * inv;
        A[256 + tid] = q[tid];
    }
}

// ---------------------------------------------------------------------------
extern "C" void kernel_launch(void* const* d_in, const int* in_sizes, int n_in,
                              void* d_out, int out_size, void* d_ws, size_t ws_size,
                              hipStream_t stream)
{
    (void)n_in; (void)ws_size;
    const float* node_attr = (const float*)d_in[0];
    const float* edge_attr = (const float*)d_in[1];
    const int*   src       = (const int*)d_in[2];
    const int*   dst       = (const int*)d_in[3];
    const int*   gid       = (const int*)d_in[4];
    const float* Wp        = (const float*)d_in[6];
    const float* bp        = (const float*)d_in[7];
    const float* Wg        = (const float*)d_in[8];
    const float* bg        = (const float*)d_in[9];
    const float* We        = (const float*)d_in[10];
    const float* be        = (const float*)d_in[11];
    const float* nb        = (const float*)d_in[12];
    const float* gwih      = (const float*)d_in[13];
    const float* gwhh      = (const float*)d_in[14];
    const float* gbih      = (const float*)d_in[15];
    const float* gbhh      = (const float*)d_in[16];
    const float* lwih      = (const float*)d_in[17];
    const float* lwhh      = (const float*)d_in[18];
    const float* lbih      = (const float*)d_in[19];
    const float* lbhh      = (const float*)d_in[20];
    const float* Ws        = (const float*)d_in[21];
    const float* bs        = (const float*)d_in[22];
    const float* pa        = (const float*)d_in[23];

    const int N = in_sizes[0] / NODE_IN;   // 10000
    const int E = in_sizes[2];             // 40000
    const int B = out_size / 1024;         // 250

    // ---- workspace layout (floats), 64-float aligned ------------------------
    float* ws = (float*)d_ws;
    size_t off = 0;
    auto alloc = [&](size_t n) { size_t o = off; off += (n + 63) & ~(size_t)63; return o; };
    // zeroed-at-start region (contiguous): deg, icnt, cl, Acat, gcnt
    size_t oDEG  = alloc(N);
    size_t oICNT = alloc(N);                     // int
    size_t oCL   = alloc((size_t)B * 128);
    size_t oACAT = alloc((size_t)B * 384);
    size_t oGCNT = alloc(B);                     // int
    size_t zero_beg = oDEG, zero_end = off;
    size_t oRP   = alloc(N + 1);                 // int
    size_t oCUR  = alloc(N);                     // int
    size_t oCSR  = alloc(E);                     // int
    size_t oH0   = alloc((size_t)N * H);
    size_t oHB   = alloc((size_t)N * H);
    size_t oEF   = alloc((size_t)E * EF);
    size_t oGL   = alloc((size_t)B * GCAP);      // int
    size_t oW2N  = alloc(896 * 64);
    size_t oWIHT = alloc(64 * 192);
    size_t oWHHT = alloc(64 * 192);
    size_t oWLT  = alloc(384 * 512);
    size_t oWST  = alloc(256 * 1024);
    size_t oAGGP = alloc((size_t)NZ * N * 64);   // 7 split-K partials
    size_t oAGGR = alloc((size_t)N * 64);
    size_t oGI   = alloc((size_t)N * 192);
    size_t oGH   = alloc((size_t)N * 192);
    size_t oG    = alloc((size_t)N * (EF * H));  // N x 896

    float* deg   = ws + oDEG;
    int*   icnt  = (int*)(ws + oICNT);
    float* clb   = ws + oCL;
    float* Acat  = ws + oACAT;
    int*   gcnt  = (int*)(ws + oGCNT);
    int*   rowp  = (int*)(ws + oRP);
    int*   cursor= (int*)(ws + oCUR);
    int*   csr   = (int*)(ws + oCSR);
    float* h0    = ws + oH0;
    float* hbuf  = ws + oHB;
    float* ef    = ws + oEF;
    int*   glist = (int*)(ws + oGL);
    float* W2n   = ws + oW2N;
    float* wihT  = ws + oWIHT;
    float* whhT  = ws + oWHHT;
    float* WlT   = ws + oWLT;
    float* WsT   = ws + oWST;
    float* aggP  = ws + oAGGP;
    float* aggR  = ws + oAGGR;
    float* gib   = ws + oGI;
    float* ghb   = ws + oGH;
    float* Gb    = ws + oG;

    const int mt64 = (N + 63) / 64;     // 157
    const int bt   = (B + 63) / 64;     // 4

    // ---- init + fused prologue ---------------------------------------------
    hipMemsetAsync(ws + zero_beg, 0, (zero_end - zero_beg) * sizeof(float), stream);
    const int nb_h0   = (N * H + 255) / 256;     // 2500
    const int nb_prep = (540672 + 255) / 256;    // 2112
    const int nb_deg  = (E + 255) / 256;         // 157
    const int nb_gl   = (N + 255) / 256;         // 40
    prep_all_k<<<nb_h0 + nb_prep + nb_deg + nb_gl, 256, 0, stream>>>(
        node_attr, Wp, bp, h0, We, be, gwih, gwhh, lwih, lwhh, Ws,
        W2n, wihT, whhT, WlT, WsT, dst, deg, icnt, gid, gcnt, glist,
        N, E, nb_h0, nb_prep, nb_deg);
    scan_k<<<1, 1024, 0, stream>>>(icnt, rowp, cursor, N);
    gate_k<<<(E + 3) / 4, 256, 0, stream>>>(h0, edge_attr, src, dst, Wg, bg, deg,
                                            ef, cursor, csr, E);

    // ---- 3 message-passing steps -------------------------------------------
    const float* hcur = h0;
    for (int step = 0; step < 3; ++step) {
        sparseG_k<<<(N + 3) / 4, 256, 0, stream>>>(hcur, ef, src, csr, rowp, Gb, N);
        aggg_k<<<dim3(mt64, NZ), 256, 0, stream>>>(Gb, W2n, aggP, N);
        sumrelu_k<<<(N * 16 + 255) / 256, 256, 0, stream>>>(aggP, nb, aggR, N);
        gigh_k<<<dim3(mt64, 6), 256, 0, stream>>>(aggR, hcur, wihT, whhT,
                                                  gib, ghb, N);
        gru_k<<<(N * H + 255) / 256, 256, 0, stream>>>(gib, ghb, gbih, gbhh,
                                                       hcur, hbuf, N);
        hcur = hbuf;
    }

    // ---- 3 Set2Set steps (fully fused per step) ----------------------------
    for (int s = 0; s < 3; ++s) {
        att256_k<<<B, 256, 0, stream>>>(h0, hbuf, WlT, lbih, lbhh, clb,
                                        glist, gcnt, Acat);
    }

    // ---- final projection + PReLU ------------------------------------------
    gemm_prelu_k<<<dim3(bt, 16), 256, 0, stream>>>(Acat, 384, WsT, 1024,
                                                   (float*)d_out, 1024,
                                                   B, 1024, 256, bs, pa);
}

// Round 12
// 477.976 us; speedup vs baseline: 5.5533x; 5.5533x over previous
//
#include <hip/hip_runtime.h>
#include <math.h>

// ---------------------------------------------------------------------------
// MPNN forward (N=10000 nodes, E=40000 edges, B=250 graphs, H=64, RD=1024)
//
// agg[d,o] = sum_{k,i} G[d,k,i] * W2n[k*64+i, o]
//   where G[d,k,:] = sum_{e in in(d)} ef[e,k] * h[src_e,:]   (N x 896)
// Dense phase: aggg (split-K z=7 -> 7 partials) -> sumrelu -> gigh -> gru.
// CSR by dst built once; sparse phase gathers h (L2-resident) only.
// NOTE (round-10 lesson): LDS reads in the FMA loop MUST be float4
// (ds_read_b128) — scalar reads blew VGPR to 256 and spilled acc to scratch
// (766 us/dispatch, 1.17 GB scratch FETCH). Pad-68 float4 body = 68 VGPR.
// ---------------------------------------------------------------------------

#define H 64
#define NODE_IN 74
#define EDGE_IN 12
#define EF 14            // EDGE_IN + gate + 1.0 (bias slot)
#define GCAP 256         // per-graph node-list capacity
#define NZ 7             // split-K factor for aggg (896 = 7*128)

__device__ __forceinline__ float sigmoidf(float x) {
    return 1.0f / (1.0f + expf(-x));
}

// ---------------------------------------------------------------------------
// 64x64-tile f32 GEMM with PReLU epilogue (final projection only).
// ---------------------------------------------------------------------------
__global__ __launch_bounds__(256)
void gemm_prelu_k(const float* __restrict__ A, int lda,
                  const float* __restrict__ B, int ldb,
                  float* __restrict__ C, int ldc,
                  int M, int N, int K,
                  const float* __restrict__ cbias,
                  const float* __restrict__ prelu_a)
{
    __shared__ float sA[64][68];
    __shared__ float sB[64][68];
    const int tid = threadIdx.x;
    const int bm  = blockIdx.x * 64;
    const int bn  = blockIdx.y * 64;
    const int tx  = tid & 15;
    const int ty  = tid >> 4;
    float acc[4][4] = {{0.f}};

    for (int k0 = 0; k0 < K; k0 += 64) {
        #pragma unroll
        for (int t = 0; t < 4; ++t) {
            int idx = tid + t * 256;
            int r   = idx >> 4;
            int c   = (idx & 15) << 2;
            float4 v = {0.f, 0.f, 0.f, 0.f};
            int gm = bm + r;
            if (gm < M)
                v = *reinterpret_cast<const float4*>(A + (size_t)gm * lda + (k0 + c));
            sA[c + 0][r] = v.x; sA[c + 1][r] = v.y;
            sA[c + 2][r] = v.z; sA[c + 3][r] = v.w;
        }
        #pragma unroll
        for (int t = 0; t < 4; ++t) {
            int idx = tid + t * 256;
            int r   = idx >> 4;
            int c   = (idx & 15) << 2;
            *reinterpret_cast<float4*>(&sB[r][c]) =
                *reinterpret_cast<const float4*>(B + (size_t)(k0 + r) * ldb + (bn + c));
        }
        __syncthreads();
        #pragma unroll
        for (int kk = 0; kk < 64; ++kk) {
            float4 av = *reinterpret_cast<const float4*>(&sA[kk][ty * 4]);
            float4 bv = *reinterpret_cast<const float4*>(&sB[kk][tx * 4]);
            float ar[4] = {av.x, av.y, av.z, av.w};
            float br[4] = {bv.x, bv.y, bv.z, bv.w};
            #pragma unroll
            for (int i = 0; i < 4; ++i)
                #pragma unroll
                for (int j = 0; j < 4; ++j)
                    acc[i][j] = fmaf(ar[i], br[j], acc[i][j]);
        }
        __syncthreads();
    }

    float pa = prelu_a[0];
    #pragma unroll
    for (int i = 0; i < 4; ++i) {
        int gm = bm + ty * 4 + i;
        if (gm < M) {
            float4 v;
            float* vv = reinterpret_cast<float*>(&v);
            #pragma unroll
            for (int j = 0; j < 4; ++j) {
                float c = acc[i][j] + cbias[bn + tx * 4 + j];
                vv[j] = (c >= 0.f) ? c : pa * c;
            }
            *reinterpret_cast<float4*>(C + (size_t)gm * ldc + bn + tx * 4) = v;
        }
    }
}

// ---------------------------------------------------------------------------
// aggP[z] = G[:, z*128:(z+1)*128] @ W2n[z*128:(z+1)*128, :]   (N x 64 each)
// grid (157, 7): blockIdx.y = z raises blocks 314 -> 1099 (occupancy lever).
// Inner body = round-7-measured 68-VGPR float4 form (pad 68, ds_read_b128).
// ---------------------------------------------------------------------------
__global__ __launch_bounds__(256)
void aggg_k(const float* __restrict__ G, const float* __restrict__ W2n,
            float* __restrict__ aggP, int M)
{
    __shared__ float sA[64][68];
    __shared__ float sB[64][68];
    const int tid = threadIdx.x;
    const int bm  = blockIdx.x * 64;
    const int z   = blockIdx.y;
    const int tx  = tid & 15;
    const int ty  = tid >> 4;
    float* C = aggP + (size_t)z * M * 64;
    float acc[4][4] = {{0.f}};

    for (int k0 = z * 128; k0 < z * 128 + 128; k0 += 64) {
        #pragma unroll
        for (int t = 0; t < 4; ++t) {
            int idx = tid + t * 256;
            int r   = idx >> 4;
            int c   = (idx & 15) << 2;
            float4 v = {0.f, 0.f, 0.f, 0.f};
            int gm = bm + r;
            if (gm < M)
                v = *reinterpret_cast<const float4*>(G + (size_t)gm * 896 + (k0 + c));
            sA[c + 0][r] = v.x; sA[c + 1][r] = v.y;
            sA[c + 2][r] = v.z; sA[c + 3][r] = v.w;
        }
        #pragma unroll
        for (int t = 0; t < 4; ++t) {
            int idx = tid + t * 256;
            int r   = idx >> 4;
            int c   = (idx & 15) << 2;
            *reinterpret_cast<float4*>(&sB[r][c]) =
                *reinterpret_cast<const float4*>(W2n + (size_t)(k0 + r) * 64 + c);
        }
        __syncthreads();
        #pragma unroll
        for (int kk = 0; kk < 64; ++kk) {
            float4 av = *reinterpret_cast<const float4*>(&sA[kk][ty * 4]);
            float4 bv = *reinterpret_cast<const float4*>(&sB[kk][tx * 4]);
            float ar[4] = {av.x, av.y, av.z, av.w};
            float br[4] = {bv.x, bv.y, bv.z, bv.w};
            #pragma unroll
            for (int i = 0; i < 4; ++i)
                #pragma unroll
                for (int j = 0; j < 4; ++j)
                    acc[i][j] = fmaf(ar[i], br[j], acc[i][j]);
        }
        __syncthreads();
    }
    #pragma unroll
    for (int i = 0; i < 4; ++i) {
        int gm = bm + ty * 4 + i;
        if (gm < M)
            *reinterpret_cast<float4*>(C + (size_t)gm * 64 + tx * 4) =
                make_float4(acc[i][0], acc[i][1], acc[i][2], acc[i][3]);
    }
}

// ---------------------------------------------------------------------------
// aggR = relu(sum_z aggP[z] + nb)   (N x 64), float4-vectorized
// ---------------------------------------------------------------------------
__global__ __launch_bounds__(256)
void sumrelu_k(const float* __restrict__ aggP, const float* __restrict__ nb,
               float* __restrict__ aggR, int M)
{
    int idx = blockIdx.x * 256 + threadIdx.x;      // float4 index
    if (idx >= M * 16) return;
    int o4 = idx & 15;
    float4 s = *reinterpret_cast<const float4*>(nb + o4 * 4);
    size_t stride = (size_t)M * 16;
    const float4* p = reinterpret_cast<const float4*>(aggP) + idx;
    #pragma unroll
    for (int z = 0; z < NZ; ++z) {
        float4 v = p[z * stride];
        s.x += v.x; s.y += v.y; s.z += v.z; s.w += v.w;
    }
    s.x = fmaxf(s.x, 0.f); s.y = fmaxf(s.y, 0.f);
    s.z = fmaxf(s.z, 0.f); s.w = fmaxf(s.w, 0.f);
    reinterpret_cast<float4*>(aggR)[idx] = s;
}

// ---------------------------------------------------------------------------
// gi / gh: grid (157, 6). y<3: gi = aggR @ wihT (col slice y);
//          y>=3: gh = h @ whhT (col slice y-3). K=64 single iteration.
// Uniform per-block pointer selects (SGPR, no in-loop branch); float4 LDS.
// ---------------------------------------------------------------------------
__global__ __launch_bounds__(256)
void gigh_k(const float* __restrict__ aggR, const float* __restrict__ h,
            const float* __restrict__ wihT, const float* __restrict__ whhT,
            float* __restrict__ gib, float* __restrict__ ghb, int M)
{
    __shared__ float sA[64][68];
    __shared__ float sB[64][68];
    const int tid = threadIdx.x;
    const int bm  = blockIdx.x * 64;
    const int yy  = blockIdx.y;
    const int sec = (yy >= 3) ? 1 : 0;
    const int bn  = (sec ? yy - 3 : yy) * 64;
    const float* A  = sec ? h : aggR;
    const float* Bm = sec ? whhT : wihT;
    float*       C  = sec ? ghb : gib;
    const int tx = tid & 15;
    const int ty = tid >> 4;
    float acc[4][4] = {{0.f}};

    #pragma unroll
    for (int t = 0; t < 4; ++t) {
        int idx = tid + t * 256;
        int r   = idx >> 4;
        int c   = (idx & 15) << 2;
        float4 v = {0.f, 0.f, 0.f, 0.f};
        int gm = bm + r;
        if (gm < M)
            v = *reinterpret_cast<const float4*>(A + (size_t)gm * 64 + c);
        sA[c + 0][r] = v.x; sA[c + 1][r] = v.y;
        sA[c + 2][r] = v.z; sA[c + 3][r] = v.w;
    }
    #pragma unroll
    for (int t = 0; t < 4; ++t) {
        int idx = tid + t * 256;
        int r   = idx >> 4;
        int c   = (idx & 15) << 2;
        *reinterpret_cast<float4*>(&sB[r][c]) =
            *reinterpret_cast<const float4*>(Bm + (size_t)r * 192 + (bn + c));
    }
    __syncthreads();
    #pragma unroll
    for (int kk = 0; kk < 64; ++kk) {
        float4 av = *reinterpret_cast<const float4*>(&sA[kk][ty * 4]);
        float4 bv = *reinterpret_cast<const float4*>(&sB[kk][tx * 4]);
        float ar[4] = {av.x, av.y, av.z, av.w};
        float br[4] = {bv.x, bv.y, bv.z, bv.w};
        #pragma unroll
        for (int i = 0; i < 4; ++i)
            #pragma unroll
            for (int j = 0; j < 4; ++j)
                acc[i][j] = fmaf(ar[i], br[j], acc[i][j]);
    }
    #pragma unroll
    for (int i = 0; i < 4; ++i) {
        int gm = bm + ty * 4 + i;
        if (gm < M)
            *reinterpret_cast<float4*>(C + (size_t)gm * 192 + bn + tx * 4) =
                make_float4(acc[i][0], acc[i][1], acc[i][2], acc[i][3]);
    }
}

// ---------------------------------------------------------------------------
// Fused prologue (block-range split): h0 | weight re-layouts | degrees | glist
// ---------------------------------------------------------------------------
__global__ __launch_bounds__(256)
void prep_all_k(const float* __restrict__ na, const float* __restrict__ Wp,
                const float* __restrict__ bp, float* __restrict__ h0,
                const float* __restrict__ We, const float* __restrict__ be,
                const float* __restrict__ wih, const float* __restrict__ whh,
                const float* __restrict__ lwih, const float* __restrict__ lwhh,
                const float* __restrict__ Ws,
                float* __restrict__ W2n, float* __restrict__ wihT,
                float* __restrict__ whhT, float* __restrict__ WlT,
                float* __restrict__ WsT,
                const int* __restrict__ dst, float* __restrict__ deg,
                int* __restrict__ icnt,
                const int* __restrict__ gid, int* __restrict__ gcnt,
                int* __restrict__ glist,
                int N, int E,
                int nb_h0, int nb_prep, int nb_deg)
{
    int b   = blockIdx.x;
    int tid = threadIdx.x;
    if (b < nb_h0) {
        int idx = b * 256 + tid;
        if (idx >= N * H) return;
        int n = idx >> 6, o = idx & 63;
        const float* x = na + (size_t)n * NODE_IN;
        const float* w = Wp + (size_t)o * NODE_IN;
        float acc = bp[o];
        #pragma unroll
        for (int k = 0; k < NODE_IN; ++k) acc = fmaf(x[k], w[k], acc);
        h0[idx] = fmaxf(acc, 0.f);
    } else if (b < nb_h0 + nb_prep) {
        int t = (b - nb_h0) * 256 + tid;
        if (t < 57344) {
            // W2n[(k*64+i)*64 + o] = k<13 ? We[(i*64+o)*13+k] : be[i*64+o]
            int ko = t >> 6, o = t & 63;
            int k = ko >> 6, i = ko & 63;
            W2n[t] = (k < 13) ? We[(size_t)(i * 64 + o) * 13 + k] : be[i * 64 + o];
        } else if (t < 69632) {
            int u = t - 57344;
            int i = u / 192, j = u % 192;
            wihT[u] = wih[(size_t)j * 64 + i];
        } else if (t < 81920) {
            int u = t - 69632;
            int i = u / 192, j = u % 192;
            whhT[u] = whh[(size_t)j * 64 + i];
        } else if (t < 278528) {
            int u = t - 81920;              // k*512 + j
            int k = u >> 9, j = u & 511;
            WlT[u] = (k < 256) ? lwih[(size_t)j * 256 + k]
                               : lwhh[(size_t)j * 128 + (k - 256)];
        } else if (t < 540672) {
            int u = t - 278528;             // k*1024 + j
            int k = u >> 10, j = u & 1023;
            WsT[u] = Ws[(size_t)j * 256 + k];
        }
    } else if (b < nb_h0 + nb_prep + nb_deg) {
        int e = (b - nb_h0 - nb_prep) * 256 + tid;
        if (e < E) {
            int d = dst[e];
            atomicAdd(&deg[d], 1.0f);
            atomicAdd(&icnt[d], 1);
        }
    } else {
        int n = (b - nb_h0 - nb_prep - nb_deg) * 256 + tid;
        if (n < N) {
            int g = gid[n];
            int p = atomicAdd(&gcnt[g], 1);
            if (p < GCAP) glist[(size_t)g * GCAP + p] = n;
        }
    }
}

// ---------------------------------------------------------------------------
// Exclusive scan of icnt[N] -> row_ptr[N+1], cursor[N]. Single block,
// shuffle-based wave scans.
// ---------------------------------------------------------------------------
__global__ __launch_bounds__(1024)
void scan_k(const int* __restrict__ icnt, int* __restrict__ row_ptr,
            int* __restrict__ cursor, int N)
{
    __shared__ int wsum[16];
    __shared__ int carrySh;
    int tid  = threadIdx.x;
    int lane = tid & 63;
    int wid  = tid >> 6;
    if (tid == 0) { carrySh = 0; row_ptr[0] = 0; }
    __syncthreads();
    for (int base = 0; base < N; base += 1024) {
        int i = base + tid;
        int v = (i < N) ? icnt[i] : 0;
        int x = v;
        #pragma unroll
        for (int off = 1; off < 64; off <<= 1) {
            int t = __shfl_up(x, off);
            if (lane >= off) x += t;
        }
        if (lane == 63) wsum[wid] = x;
        __syncthreads();
        if (wid == 0) {
            int s = (lane < 16) ? wsum[lane] : 0;
            #pragma unroll
            for (int off = 1; off < 16; off <<= 1) {
                int t = __shfl_up(s, off);
                if (lane >= off) s += t;
            }
            if (lane < 16) wsum[lane] = s;
        }
        __syncthreads();
        int woff = (wid > 0) ? wsum[wid - 1] : 0;
        int incl = x + woff + carrySh;
        if (i < N) { row_ptr[i + 1] = incl; cursor[i] = incl - v; }
        __syncthreads();
        if (tid == 1023) carrySh = incl;
        __syncthreads();
    }
}

// ---------------------------------------------------------------------------
// FALayer gate -> ef[e] = [edge_attr(12), gate, 1.0]; lane 14 fills CSR slot.
// ---------------------------------------------------------------------------
__global__ __launch_bounds__(256)
void gate_k(const float* __restrict__ h0, const float* __restrict__ ea,
            const int* __restrict__ src, const int* __restrict__ dst,
            const float* __restrict__ Wg, const float* __restrict__ bg,
            const float* __restrict__ deg, float* __restrict__ ef,
            int* __restrict__ cursor, int* __restrict__ csr_eid, int E)
{
    int e    = blockIdx.x * 4 + (threadIdx.x >> 6);
    int lane = threadIdx.x & 63;
    if (e >= E) return;
    int s = src[e], d = dst[e];
    float v = Wg[lane]      * h0[(size_t)d * H + lane]
            + Wg[H + lane]  * h0[(size_t)s * H + lane];
    #pragma unroll
    for (int off = 32; off; off >>= 1) v += __shfl_xor(v, off);
    if (lane < EF) {
        float out;
        if (lane < EDGE_IN) out = ea[(size_t)e * EDGE_IN + lane];
        else if (lane == EDGE_IN) {
            float t = tanhf(v + bg[0]);
            out = 0.3f + t * deg[d] * deg[s];
        } else out = 1.0f;
        ef[(size_t)e * EF + lane] = out;
    } else if (lane == EF) {
        int pos = atomicAdd(&cursor[d], 1);
        csr_eid[pos] = e;
    }
}

// ---------------------------------------------------------------------------
// Sparse phase: G[d,k,:] = sum_{e in in(d)} ef[e,k] * h[src_e,:]
// One wave per dst node (lane = h channel); h is L2-resident (2.5 MB).
// ---------------------------------------------------------------------------
__global__ __launch_bounds__(256)
void sparseG_k(const float* __restrict__ h, const float* __restrict__ ef,
               const int* __restrict__ src, const int* __restrict__ csr_eid,
               const int* __restrict__ rowp, float* __restrict__ G, int N)
{
    int n    = blockIdx.x * 4 + (threadIdx.x >> 6);
    int lane = threadIdx.x & 63;
    if (n >= N) return;
    float g[EF];
    #pragma unroll
    for (int k = 0; k < EF; ++k) g[k] = 0.f;
    int p0 = rowp[n], p1 = rowp[n + 1];
    for (int p = p0; p < p1; ++p) {
        int e = csr_eid[p];
        float hv = h[(size_t)src[e] * H + lane];
        const float* f = ef + (size_t)e * EF;
        #pragma unroll
        for (int k = 0; k < EF; ++k) g[k] = fmaf(f[k], hv, g[k]);
    }
    float* Gr = G + (size_t)n * (EF * H);
    #pragma unroll
    for (int k = 0; k < EF; ++k) Gr[k * H + lane] = g[k];
}

// ---------------------------------------------------------------------------
// GRU elementwise (torch gate order r,z,n); biases folded here.
// ---------------------------------------------------------------------------
__global__ __launch_bounds__(256)
void gru_k(const float* __restrict__ gi, const float* __restrict__ gh,
           const float* __restrict__ bih, const float* __restrict__ bhh,
           const float* __restrict__ hin, float* __restrict__ hout, int N)
{
    int idx = blockIdx.x * 256 + threadIdx.x;
    if (idx >= N * H) return;
    int n = idx >> 6, o = idx & 63;
    const float* gin = gi + (size_t)n * 192;
    const float* ghn = gh + (size_t)n * 192;
    float r  = sigmoidf(gin[o]       + bih[o]       + ghn[o]       + bhh[o]);
    float z  = sigmoidf(gin[64 + o]  + bih[64 + o]  + ghn[64 + o]  + bhh[64 + o]);
    float gn = ghn[128 + o] + bhh[128 + o];
    float ng = tanhf(gin[128 + o] + bih[128 + o] + r * gn);
    float hv = hin[idx];
    hout[idx] = (1.f - z) * ng + z * hv;
}

// ---------------------------------------------------------------------------
// Fully fused Set2Set step, one 256-thread block per graph.
// Acat[b] = [q_star (q|readout) (256) | hl (128)].
// ---------------------------------------------------------------------------
__global__ __launch_bounds__(256)
void att256_k(const float* __restrict__ h0, const float* __restrict__ h,
              const float* __restrict__ WlT,
              const float* __restrict__ lbih, const float* __restrict__ lbhh,
              float* __restrict__ cl,
              const int* __restrict__ glist, const int* __restrict__ gcnt,
              float* __restrict__ Acat)
{
    int b    = blockIdx.x;
    int tid  = threadIdx.x;
    int lane = tid & 63;
    int wid  = tid >> 6;
    __shared__ float acatS[384];
    __shared__ float g4s[512];
    __shared__ float q[128];
    __shared__ float sc[GCAP];
    __shared__ float red[8];

    for (int j = tid; j < 384; j += 256) acatS[j] = Acat[(size_t)b * 384 + j];
    __syncthreads();

    for (int j = tid; j < 512; j += 256) {
        float s = 0.f;
        for (int k = 0; k < 384; ++k)
            s = fmaf(acatS[k], WlT[(size_t)k * 512 + j], s);
        g4s[j] = s;
    }
    __syncthreads();

    if (tid < 128) {
        int d = tid;
        float ii = sigmoidf(g4s[d]       + lbih[d]       + lbhh[d]);
        float ff = sigmoidf(g4s[128 + d] + lbih[128 + d] + lbhh[128 + d]);
        float gg = tanhf  (g4s[256 + d] + lbih[256 + d] + lbhh[256 + d]);
        float oo = sigmoidf(g4s[384 + d] + lbih[384 + d] + lbhh[384 + d]);
        float c  = ff * cl[(size_t)b * 128 + d] + ii * gg;
        cl[(size_t)b * 128 + d] = c;
        q[d] = oo * tanhf(c);
    }
    __syncthreads();

    int c = gcnt[b]; if (c > GCAP) c = GCAP;

    float lmax = -INFINITY;
    for (int i = wid; i < c; i += 4) {
        int n = glist[(size_t)b * GCAP + i];
        float v = h0[(size_t)n * H + lane] * q[lane]
                + h [(size_t)n * H + lane] * q[64 + lane];
        #pragma unroll
        for (int off = 32; off; off >>= 1) v += __shfl_xor(v, off);
        if (lane == 0) sc[i] = v;
        lmax = fmaxf(lmax, v);
    }
    if (lane == 0) red[wid] = lmax;
    __syncthreads();
    lmax = fmaxf(fmaxf(red[0], red[1]), fmaxf(red[2], red[3]));

    float lsum = 0.f;
    for (int i = tid; i < c; i += 256) {
        float e = expf(sc[i] - lmax);
        sc[i] = e;
        lsum += e;
    }
    #pragma unroll
    for (int off = 32; off; off >>= 1) lsum += __shfl_xor(lsum, off);
    if (lane == 0) red[4 + wid] = lsum;
    __syncthreads();
    float inv = 1.f / (red[4] + red[5] + red[6] + red[7]);

    float r = 0.f;
    if (tid < 128) {
        const float* srcf = (tid < 64) ? h0 : h;
        for (int i = 0; i < c; ++i) {
            int n = glist[(size_t)b * GCAP + i];
            r = fmaf(sc[i], srcf[(size_t)n * H + lane], r);
        }
    }
    float* A = Acat + (size_t)b * 384;
    if (tid < 128) {
        A[tid]       = q[tid];
        A[128 + tid] = r * inv;
        A[256 + tid] = q[tid];
    }
}

// ---------------------------------------------------------------------------
extern "C" void kernel_launch(void* const* d_in, const int* in_sizes, int n_in,
                              void* d_out, int out_size, void* d_ws, size_t ws_size,
                              hipStream_t stream)
{
    (void)n_in; (void)ws_size;
    const float* node_attr = (const float*)d_in[0];
    const float* edge_attr = (const float*)d_in[1];
    const int*   src       = (const int*)d_in[2];
    const int*   dst       = (const int*)d_in[3];
    const int*   gid       = (const int*)d_in[4];
    const float* Wp        = (const float*)d_in[6];
    const float* bp        = (const float*)d_in[7];
    const float* Wg        = (const float*)d_in[8];
    const float* bg        = (const float*)d_in[9];
    const float* We        = (const float*)d_in[10];
    const float* be        = (const float*)d_in[11];
    const float* nb        = (const float*)d_in[12];
    const float* gwih      = (const float*)d_in[13];
    const float* gwhh      = (const float*)d_in[14];
    const float* gbih      = (const float*)d_in[15];
    const float* gbhh      = (const float*)d_in[16];
    const float* lwih      = (const float*)d_in[17];
    const float* lwhh      = (const float*)d_in[18];
    const float* lbih      = (const float*)d_in[19];
    const float* lbhh      = (const float*)d_in[20];
    const float* Ws        = (const float*)d_in[21];
    const float* bs        = (const float*)d_in[22];
    const float* pa        = (const float*)d_in[23];

    const int N = in_sizes[0] / NODE_IN;   // 10000
    const int E = in_sizes[2];             // 40000
    const int B = out_size / 1024;         // 250

    // ---- workspace layout (floats), 64-float aligned ------------------------
    float* ws = (float*)d_ws;
    size_t off = 0;
    auto alloc = [&](size_t n) { size_t o = off; off += (n + 63) & ~(size_t)63; return o; };
    // zeroed-at-start region (contiguous): deg, icnt, cl, Acat, gcnt
    size_t oDEG  = alloc(N);
    size_t oICNT = alloc(N);                     // int
    size_t oCL   = alloc((size_t)B * 128);
    size_t oACAT = alloc((size_t)B * 384);
    size_t oGCNT = alloc(B);                     // int
    size_t zero_beg = oDEG, zero_end = off;
    size_t oRP   = alloc(N + 1);                 // int
    size_t oCUR  = alloc(N);                     // int
    size_t oCSR  = alloc(E);                     // int
    size_t oH0   = alloc((size_t)N * H);
    size_t oHB   = alloc((size_t)N * H);
    size_t oEF   = alloc((size_t)E * EF);
    size_t oGL   = alloc((size_t)B * GCAP);      // int
    size_t oW2N  = alloc(896 * 64);
    size_t oWIHT = alloc(64 * 192);
    size_t oWHHT = alloc(64 * 192);
    size_t oWLT  = alloc(384 * 512);
    size_t oWST  = alloc(256 * 1024);
    size_t oAGGP = alloc((size_t)NZ * N * 64);   // 7 split-K partials
    size_t oAGGR = alloc((size_t)N * 64);
    size_t oGI   = alloc((size_t)N * 192);
    size_t oGH   = alloc((size_t)N * 192);
    size_t oG    = alloc((size_t)N * (EF * H));  // N x 896

    float* deg   = ws + oDEG;
    int*   icnt  = (int*)(ws + oICNT);
    float* clb   = ws + oCL;
    float* Acat  = ws + oACAT;
    int*   gcnt  = (int*)(ws + oGCNT);
    int*   rowp  = (int*)(ws + oRP);
    int*   cursor= (int*)(ws + oCUR);
    int*   csr   = (int*)(ws + oCSR);
    float* h0    = ws + oH0;
    float* hbuf  = ws + oHB;
    float* ef    = ws + oEF;
    int*   glist = (int*)(ws + oGL);
    float* W2n   = ws + oW2N;
    float* wihT  = ws + oWIHT;
    float* whhT  = ws + oWHHT;
    float* WlT   = ws + oWLT;
    float* WsT   = ws + oWST;
    float* aggP  = ws + oAGGP;
    float* aggR  = ws + oAGGR;
    float* gib   = ws + oGI;
    float* ghb   = ws + oGH;
    float* Gb    = ws + oG;

    const int mt64 = (N + 63) / 64;     // 157
    const int bt   = (B + 63) / 64;     // 4

    // ---- init + fused prologue ---------------------------------------------
    hipMemsetAsync(ws + zero_beg, 0, (zero_end - zero_beg) * sizeof(float), stream);
    const int nb_h0   = (N * H + 255) / 256;     // 2500
    const int nb_prep = (540672 + 255) / 256;    // 2112
    const int nb_deg  = (E + 255) / 256;         // 157
    const int nb_gl   = (N + 255) / 256;         // 40
    prep_all_k<<<nb_h0 + nb_prep + nb_deg + nb_gl, 256, 0, stream>>>(
        node_attr, Wp, bp, h0, We, be, gwih, gwhh, lwih, lwhh, Ws,
        W2n, wihT, whhT, WlT, WsT, dst, deg, icnt, gid, gcnt, glist,
        N, E, nb_h0, nb_prep, nb_deg);
    scan_k<<<1, 1024, 0, stream>>>(icnt, rowp, cursor, N);
    gate_k<<<(E + 3) / 4, 256, 0, stream>>>(h0, edge_attr, src, dst, Wg, bg, deg,
                                            ef, cursor, csr, E);

    // ---- 3 message-passing steps -------------------------------------------
    const float* hcur = h0;
    for (int step = 0; step < 3; ++step) {
        sparseG_k<<<(N + 3) / 4, 256, 0, stream>>>(hcur, ef, src, csr, rowp, Gb, N);
        aggg_k<<<dim3(mt64, NZ), 256, 0, stream>>>(Gb, W2n, aggP, N);
        sumrelu_k<<<(N * 16 + 255) / 256, 256, 0, stream>>>(aggP, nb, aggR, N);
        gigh_k<<<dim3(mt64, 6), 256, 0, stream>>>(aggR, hcur, wihT, whhT,
                                                  gib, ghb, N);
        gru_k<<<(N * H + 255) / 256, 256, 0, stream>>>(gib, ghb, gbih, gbhh,
                                                       hcur, hbuf, N);
        hcur = hbuf;
    }

    // ---- 3 Set2Set steps (fully fused per step) ----------------------------
    for (int s = 0; s < 3; ++s) {
        att256_k<<<B, 256, 0, stream>>>(h0, hbuf, WlT, lbih, lbhh, clb,
                                        glist, gcnt, Acat);
    }

    // ---- final projection + PReLU ------------------------------------------
    gemm_prelu_k<<<dim3(bt, 16), 256, 0, stream>>>(Acat, 384, WsT, 1024,
                                                   (float*)d_out, 1024,
                                                   B, 1024, 256, bs, pa);
}